// Round 2
// baseline (1342.160 us; speedup 1.0000x reference)
//
#include <hip/hip_runtime.h>
#include <hip/hip_bf16.h>
#include <cstdint>

#define N_ROWS 65536
#define FEA    256
#define MEM    2000
#define MEMP   2048
#define LAMBD  0.0025f
#define SEPS   1e-6f
#define RBLK   64
#define NW     16

typedef __attribute__((ext_vector_type(8))) _Float16 f16x8;
typedef __attribute__((ext_vector_type(8))) short    bf16x8;
typedef __attribute__((ext_vector_type(4))) float    f32x4;

__device__ __forceinline__ short f2bf(float f) {
    union { float f; uint32_t u; } v; v.f = f;
    uint32_t r = v.u + 0x7fffu + ((v.u >> 16) & 1u);
    return (short)(r >> 16);
}

// ---------- prep: W f32[2000][256] -> Whl fp16[2048][512] (hi|lo2048 per 32k-chunk), Wt bf16[256][2048]
__global__ __launch_bounds__(256) void prep_kernel(const float* __restrict__ W,
                                                   _Float16* __restrict__ Whl,
                                                   short* __restrict__ Wt) {
    __shared__ float tile[8][260];
    const int t  = threadIdx.x;
    const int m0 = blockIdx.x * 8;
    {
        int row = t >> 5, col = (t & 31) * 8, m = m0 + row;
        if (m < MEM) {
            f32x4 a = *(const f32x4*)(W + (size_t)m * FEA + col);
            f32x4 b = *(const f32x4*)(W + (size_t)m * FEA + col + 4);
            #pragma unroll
            for (int u = 0; u < 4; ++u) { tile[row][col+u] = a[u]; tile[row][col+4+u] = b[u]; }
        } else {
            #pragma unroll
            for (int u = 0; u < 8; ++u) tile[row][col+u] = 0.f;
        }
    }
    __syncthreads();
    {   // Whl: per row, 512 halfs laid out [chunk c][0..31 = hi(k=c*32+..), 32..63 = lo*2048]
        int row = t >> 5, p0 = (t & 31) * 16;
        _Float16 buf[16];
        #pragma unroll
        for (int u = 0; u < 16; ++u) {
            int p = p0 + u, c = p >> 6, r = p & 63, k = c * 32 + (r & 31);
            float w = tile[row][k];
            _Float16 h = (_Float16)w;
            buf[u] = (r < 32) ? h : (_Float16)((w - (float)h) * 2048.0f);
        }
        _Float16* dst = Whl + (size_t)(m0 + row) * 512 + p0;
        *(f16x8*)dst       = *(f16x8*)&buf[0];
        *(f16x8*)(dst + 8) = *(f16x8*)&buf[8];
    }
    {   // Wt[f][m] transpose (zeros for m>=2000 come from zeroed tile rows)
        short buf[8];
        #pragma unroll
        for (int j = 0; j < 8; ++j) buf[j] = f2bf(tile[j][t]);
        *(bf16x8*)(Wt + (size_t)t * MEMP + m0) = *(bf16x8*)&buf[0];
    }
}

// ---------- cross-wave reduction helper (max or sum) over the 64 rows of the block
__device__ __forceinline__ void cross_reduce(float red[4][4], float (&redbuf)[NW][64],
                                             float (&redglob)[64], float out[4][4],
                                             int tid, int wid, int lane, int q, bool ismax) {
    #pragma unroll
    for (int m = 1; m < 16; m <<= 1)
        #pragma unroll
        for (int g = 0; g < 4; ++g)
            #pragma unroll
            for (int i = 0; i < 4; ++i) {
                float o = __shfl_xor(red[g][i], m, 64);
                red[g][i] = ismax ? fmaxf(red[g][i], o) : (red[g][i] + o);
            }
    if ((lane & 15) == 0) {
        #pragma unroll
        for (int g = 0; g < 4; ++g)
            #pragma unroll
            for (int i = 0; i < 4; ++i) redbuf[wid][g * 16 + q * 4 + i] = red[g][i];
    }
    __syncthreads();
    if (tid < 64) {
        float v = redbuf[0][tid];
        #pragma unroll
        for (int w = 1; w < NW; ++w) v = ismax ? fmaxf(v, redbuf[w][tid]) : (v + redbuf[w][tid]);
        redglob[tid] = v;
    }
    __syncthreads();
    #pragma unroll
    for (int g = 0; g < 4; ++g)
        #pragma unroll
        for (int i = 0; i < 4; ++i) out[g][i] = redglob[g * 16 + q * 4 + i];
    __syncthreads();
}

// ---------- kernel 2: logits (fp16x2 split MFMA) + softmax + shrink + renorm -> att f32
__global__ __launch_bounds__(1024) void score_kernel(const float* __restrict__ x,
                                                     const _Float16* __restrict__ Whl,
                                                     const float* __restrict__ temp,
                                                     float* __restrict__ att) {
    __shared__ _Float16 ah_s[64][264];
    __shared__ _Float16 al_s[64][264];
    __shared__ float redbuf[NW][64];
    __shared__ float redglob[64];
    const int tid  = threadIdx.x;
    const int lane = tid & 63;
    const int wid  = tid >> 6;
    const int lr   = lane & 15;
    const int q    = lane >> 4;
    const int lk   = q * 8;
    const size_t r0 = (size_t)blockIdx.x * RBLK;
    const float invT = 1.0f / temp[0];

    {   // stage clip(x) -> fp16 hi/lo(x2048) in LDS
        const int row = tid >> 4, col = (tid & 15) * 16;
        const float* xp = x + (r0 + row) * FEA + col;
        #pragma unroll
        for (int u = 0; u < 16; u += 4) {
            f32x4 v = *(const f32x4*)(xp + u);
            #pragma unroll
            for (int w = 0; w < 4; ++w) {
                float f = fminf(fmaxf(v[w], -10.f), 10.f);
                _Float16 h = (_Float16)f;
                ah_s[row][col + u + w] = h;
                al_s[row][col + u + w] = (_Float16)((f - (float)h) * 2048.0f);
            }
        }
    }
    __syncthreads();

    f32x4 acc[8][4];
    #pragma unroll
    for (int j = 0; j < 8; ++j)
        #pragma unroll
        for (int g = 0; g < 4; ++g) acc[j][g] = (f32x4){0.f, 0.f, 0.f, 0.f};

    const _Float16* wbase = Whl + (size_t)(wid * 16 + lr) * 512 + lk;

    #pragma unroll 1
    for (int c = 0; c < 8; ++c) {
        f16x8 ah[4], al[4];
        #pragma unroll
        for (int g = 0; g < 4; ++g) {
            ah[g] = *(const f16x8*)&ah_s[g * 16 + lr][c * 32 + lk];
            al[g] = *(const f16x8*)&al_s[g * 16 + lr][c * 32 + lk];
        }
        #pragma unroll
        for (int j = 0; j < 8; ++j) {
            const _Float16* wp = wbase + (size_t)j * 131072 + c * 64;
            f16x8 bh = *(const f16x8*)wp;
            f16x8 bl = *(const f16x8*)(wp + 32);
            #pragma unroll
            for (int g = 0; g < 4; ++g) {
                f32x4 z = (f32x4){0.f, 0.f, 0.f, 0.f};
                f32x4 tcr = __builtin_amdgcn_mfma_f32_16x16x32_f16(al[g], bh, z, 0, 0, 0);
                tcr = __builtin_amdgcn_mfma_f32_16x16x32_f16(ah[g], bl, tcr, 0, 0, 0);
                acc[j][g] += tcr * (1.0f / 2048.0f);
                acc[j][g] = __builtin_amdgcn_mfma_f32_16x16x32_f16(ah[g], bh, acc[j][g], 0, 0, 0);
            }
        }
    }

    const bool v7 = (wid < 13);   // tile j==7 valid (t = wid+112 < 125)
    float red[4][4], M[4][4], Z[4][4], WS[4][4];

    // ---- row max
    #pragma unroll
    for (int g = 0; g < 4; ++g)
        #pragma unroll
        for (int i = 0; i < 4; ++i) red[g][i] = -3.0e38f;
    #pragma unroll
    for (int j = 0; j < 8; ++j) {
        if (j < 7 || v7) {
            #pragma unroll
            for (int g = 0; g < 4; ++g)
                #pragma unroll
                for (int i = 0; i < 4; ++i) red[g][i] = fmaxf(red[g][i], acc[j][g][i]);
        }
    }
    cross_reduce(red, redbuf, redglob, M, tid, wid, lane, q, true);

    // ---- exp (invalid tiles -> 0)
    #pragma unroll
    for (int j = 0; j < 8; ++j) {
        const bool v = (j < 7) || v7;
        #pragma unroll
        for (int g = 0; g < 4; ++g)
            #pragma unroll
            for (int i = 0; i < 4; ++i) {
                float s = acc[j][g][i];
                acc[j][g][i] = v ? __expf((s - M[g][i]) * invT) : 0.0f;
            }
    }

    // ---- sum Z
    #pragma unroll
    for (int g = 0; g < 4; ++g)
        #pragma unroll
        for (int i = 0; i < 4; ++i) red[g][i] = 0.f;
    #pragma unroll
    for (int j = 0; j < 8; ++j)
        #pragma unroll
        for (int g = 0; g < 4; ++g)
            #pragma unroll
            for (int i = 0; i < 4; ++i) red[g][i] += acc[j][g][i];
    cross_reduce(red, redbuf, redglob, Z, tid, wid, lane, q, false);

    float rz[4][4];
    #pragma unroll
    for (int g = 0; g < 4; ++g)
        #pragma unroll
        for (int i = 0; i < 4; ++i) rz[g][i] = 1.0f / Z[g][i];

    // ---- softmax value + hard_shrink_relu, in place
    #pragma unroll
    for (int j = 0; j < 8; ++j)
        #pragma unroll
        for (int g = 0; g < 4; ++g)
            #pragma unroll
            for (int i = 0; i < 4; ++i) {
                float a = acc[j][g][i] * rz[g][i];
                float d = a - LAMBD;
                float o = (d > 0.f) ? (d * a) / (d + SEPS) : 0.f;
                acc[j][g][i] = o;
            }

    // ---- weight_sum
    #pragma unroll
    for (int g = 0; g < 4; ++g)
        #pragma unroll
        for (int i = 0; i < 4; ++i) red[g][i] = 0.f;
    #pragma unroll
    for (int j = 0; j < 8; ++j)
        #pragma unroll
        for (int g = 0; g < 4; ++g)
            #pragma unroll
            for (int i = 0; i < 4; ++i) red[g][i] += acc[j][g][i];
    cross_reduce(red, redbuf, redglob, WS, tid, wid, lane, q, false);

    const float inv_m = 1.0f / (float)MEM;
    float scl[4][4];
    #pragma unroll
    for (int g = 0; g < 4; ++g)
        #pragma unroll
        for (int i = 0; i < 4; ++i) scl[g][i] = 1.0f / (WS[g][i] + 1e-8f);

    // ---- store att f32
    #pragma unroll
    for (int j = 0; j < 8; ++j) {
        if (j < 7 || v7) {
            const int mcol = (wid + 16 * j) * 16 + lr;
            #pragma unroll
            for (int g = 0; g < 4; ++g)
                #pragma unroll
                for (int i = 0; i < 4; ++i) {
                    float vv = (WS[g][i] < 1e-8f) ? inv_m : acc[j][g][i] * scl[g][i];
                    att[(r0 + g * 16 + q * 4 + i) * (size_t)MEM + mcol] = vv;
                }
        }
    }
}

// ---------- kernel 3: out = att(f32->bf16) @ W, 128-row tiles, LDS double-buffered
__global__ __launch_bounds__(512) void gemm2_kernel(const float* __restrict__ att,
                                                    const short* __restrict__ Wt,
                                                    float* __restrict__ out) {
    __shared__ short Asm[2][128][40];
    __shared__ short Bsm[2][256][40];
    const int tid  = threadIdx.x;
    const int lane = tid & 63;
    const int wid  = tid >> 6;
    const int rg   = wid >> 2;
    const int cg   = wid & 3;
    const int lr   = lane & 15;
    const int lk   = (lane >> 4) * 8;
    const size_t r0 = (size_t)blockIdx.x * 128;

    const int sa_row = tid >> 2, sa_ko = (tid & 3) * 8;
    const int sb_f   = tid >> 1, sb_ko = (tid & 1) * 16;

    auto stage = [&](int buf, int kc) {
        const int k0 = kc * 32;
        {   // A: att f32 -> bf16
            int k = k0 + sa_ko;
            short b[8];
            if (k < MEM) {
                const float* ap = att + (r0 + sa_row) * (size_t)MEM + k;
                f32x4 v0 = *(const f32x4*)ap;
                f32x4 v1 = *(const f32x4*)(ap + 4);
                #pragma unroll
                for (int u = 0; u < 4; ++u) { b[u] = f2bf(v0[u]); b[4+u] = f2bf(v1[u]); }
            } else {
                #pragma unroll
                for (int u = 0; u < 8; ++u) b[u] = 0;
            }
            *(bf16x8*)&Asm[buf][sa_row][sa_ko] = *(bf16x8*)&b[0];
        }
        {   // B: Wt (bf16, padded to 2048)
            const short* wp = Wt + (size_t)sb_f * MEMP + k0 + sb_ko;
            bf16x8 b0 = *(const bf16x8*)wp;
            bf16x8 b1 = *(const bf16x8*)(wp + 8);
            *(bf16x8*)&Bsm[buf][sb_f][sb_ko]     = b0;
            *(bf16x8*)&Bsm[buf][sb_f][sb_ko + 8] = b1;
        }
    };

    f32x4 acc[4][4];
    #pragma unroll
    for (int i = 0; i < 4; ++i)
        #pragma unroll
        for (int j = 0; j < 4; ++j) acc[i][j] = (f32x4){0.f, 0.f, 0.f, 0.f};

    stage(0, 0);
    int cur = 0;
    for (int kc = 0; kc < 63; ++kc) {
        __syncthreads();
        if (kc + 1 < 63) stage(cur ^ 1, kc + 1);
        bf16x8 a_[4], b_[4];
        #pragma unroll
        for (int i = 0; i < 4; ++i) a_[i] = *(const bf16x8*)&Asm[cur][rg * 64 + i * 16 + lr][lk];
        #pragma unroll
        for (int j = 0; j < 4; ++j) b_[j] = *(const bf16x8*)&Bsm[cur][cg * 64 + j * 16 + lr][lk];
        #pragma unroll
        for (int i = 0; i < 4; ++i)
            #pragma unroll
            for (int j = 0; j < 4; ++j)
                acc[i][j] = __builtin_amdgcn_mfma_f32_16x16x32_bf16(a_[i], b_[j], acc[i][j], 0, 0, 0);
        cur ^= 1;
    }

    #pragma unroll
    for (int i = 0; i < 4; ++i)
        #pragma unroll
        for (int j = 0; j < 4; ++j)
            #pragma unroll
            for (int ii = 0; ii < 4; ++ii) {
                size_t row = r0 + rg * 64 + i * 16 + (lane >> 4) * 4 + ii;
                out[row * FEA + cg * 64 + j * 16 + lr] = acc[i][j][ii];
            }
}

extern "C" void kernel_launch(void* const* d_in, const int* in_sizes, int n_in,
                              void* d_out, int out_size, void* d_ws, size_t ws_size,
                              hipStream_t stream) {
    const float* x = (const float*)d_in[0];
    const float* W = (const float*)d_in[1];
    const float* T = (const float*)d_in[2];
    float* out = (float*)d_out;
    float* att = out + (size_t)N_ROWS * FEA;
    _Float16* Whl = (_Float16*)d_ws;                       // 2 MiB
    short*    Wt  = (short*)((char*)d_ws + (2u << 20));    // 1 MiB

    prep_kernel<<<dim3(256), dim3(256), 0, stream>>>(W, Whl, Wt);
    score_kernel<<<dim3(N_ROWS / RBLK), dim3(1024), 0, stream>>>(x, Whl, T, att);
    gemm2_kernel<<<dim3(N_ROWS / 128), dim3(512), 0, stream>>>(att, Wt, out);
}